// Round 13
// baseline (111.782 us; speedup 1.0000x reference)
//
#include <hip/hip_runtime.h>
#include <hip/hip_bf16.h>

typedef __attribute__((ext_vector_type(8))) short bfx8;
typedef __attribute__((ext_vector_type(4))) short bfx4;
typedef __attribute__((ext_vector_type(4))) float fx4;

static __device__ __forceinline__ short f2bf(float f) {
  union { float f; unsigned u; } v; v.f = f;
  unsigned r = v.u + 0x7fffu + ((v.u >> 16) & 1u);
  return (short)(r >> 16);
}

static __device__ __forceinline__ void gld16(const void* g, void* l) {
  __builtin_amdgcn_global_load_lds(
      (const __attribute__((address_space(1))) void*)g,
      (__attribute__((address_space(3))) void*)l, 16, 0, 0);
}

constexpr int Bz = 8, Sq = 512, Em = 1024, Hn = 16, Dh = 64;
constexpr int Mrows = Bz * Sq;             // 4096
constexpr size_t NE = (size_t)Mrows * Em;  // 4,194,304
constexpr size_t WE = (size_t)Em * Em;     // 1,048,576

// ---------------- f32 -> bf16 pre-convert (unchanged) ----------------
__global__ __launch_bounds__(256) void convert_kernel(
    const float* __restrict__ q, const float* __restrict__ k,
    const float* __restrict__ v,
    const float* __restrict__ Wq, const float* __restrict__ Wk,
    const float* __restrict__ Wv, const float* __restrict__ Wo,
    short* __restrict__ qx, short* __restrict__ kx, short* __restrict__ vx,
    short* __restrict__ wqb, short* __restrict__ wkb,
    short* __restrict__ wvb, short* __restrict__ wob)
{
  const size_t c = (size_t)blockIdx.x * 256 + threadIdx.x;
  constexpr size_t CI = NE / 8;
  constexpr size_t CW = WE / 8;
  const float* src; short* dst; size_t off;
  if (c < 3 * CI) {
    const int sgi = (int)(c / CI);
    src = sgi == 0 ? q : sgi == 1 ? k : v;
    dst = sgi == 0 ? qx : sgi == 1 ? kx : vx;
    off = (c - (size_t)sgi * CI) * 8;
  } else {
    const size_t w = c - 3 * CI;
    const int sgi = (int)(w / CW);
    src = sgi == 0 ? Wq : sgi == 1 ? Wk : sgi == 2 ? Wv : Wo;
    dst = sgi == 0 ? wqb : sgi == 1 ? wkb : sgi == 2 ? wvb : wob;
    off = (w - (size_t)sgi * CW) * 8;
  }
  fx4 a = *(const fx4*)(src + off);
  fx4 b = *(const fx4*)(src + off + 4);
  bfx8 o = { f2bf(a[0]), f2bf(a[1]), f2bf(a[2]), f2bf(a[3]),
             f2bf(b[0]), f2bf(b[1]), f2bf(b[2]), f2bf(b[3]) };
  *(bfx8*)(dst + off) = o;
}

// ---------------- gemm_qkv: 256x256, 8 waves, BK=32, 4-slot counted pipeline ----------------
// LDS 128KB = 4 slots x 32KB {A[256][32] | B[256][32]}. Tile kt: stage(kt+3)
// into slot (kt+3)&3 (4 gld16/thr) -> s_waitcnt vmcnt(12) (waits stage(kt)
// only; 3 stages stay in flight, NEVER drains in-loop) -> s_barrier ->
// 12 ds_read_b128 -> setprio(1) 32 MFMA setprio(0) -> s_barrier.
// WAR: stage(kt+3) targets slot read at kt-1 (reads retired pre-barrier).
// XOR swizzle both-sides at 16B-chunk granularity: LDS[R][c'] = src[R][c'^((R>>1)&3)].
__global__ __launch_bounds__(512, 2) void gemm_qkv_bf16(
    const short* __restrict__ qx, const short* __restrict__ kx,
    const short* __restrict__ vx,
    const short* __restrict__ Wqb, const short* __restrict__ Wkb,
    const short* __restrict__ Wvb,
    const float* __restrict__ bq, const float* __restrict__ bk,
    const float* __restrict__ bv,
    const float* __restrict__ pos,
    short* __restrict__ qb, short* __restrict__ kb, short* __restrict__ vb)
{
  __shared__ short SM[65536];   // 128KB = 4 x 16384 shorts

  const int z = blockIdx.z;
  const short* X = (z == 0) ? qx : (z == 1) ? kx : vx;
  const short* W = (z == 0) ? Wqb : (z == 1) ? Wkb : Wvb;
  const float* bias = (z == 0) ? bq : (z == 1) ? bk : bv;
  short* dst = (z == 0) ? qb : (z == 1) ? kb : vb;

  const int t0b = blockIdx.x * 256;   // tokens (fast axis -> XCD locality)
  const int f0 = blockIdx.y * 256;    // features
  const int t = threadIdx.x, lane = t & 63, wave = t >> 6;
  const int wr = wave >> 2;           // feature half
  const int wn = wave & 3;            // token quarter
  const int fr = lane & 15, fq = lane >> 4;

  // staging: gld g covers row g*128 + (t>>2), source col chunk (t&3)^((t>>3)&3)
  const int srow = t >> 2;
  const int scol = ((t & 3) ^ ((t >> 3) & 3)) * 8;
  const short* gA = W + (size_t)(f0 + srow) * Em + scol;
  const short* gB = X + (size_t)(t0b + srow) * Em + scol;
  const int ldst = wave * 512;   // + g*4096 (A), +8192 (B)

  auto stage = [&](int ktn) {
    short* sl = SM + (ktn & 3) * 16384;
    const int ko = ktn * 32;
#pragma unroll
    for (int g = 0; g < 2; ++g) {
      gld16(gA + (size_t)(g * 128) * Em + ko, sl + g * 4096 + ldst);
      gld16(gB + (size_t)(g * 128) * Em + ko, sl + 8192 + g * 4096 + ldst);
    }
  };

  // read-side swizzled chunk: c' = fq ^ ((R>>1)&3) = fq ^ ((fr>>1)&3)  (R=16a+fr)
  const int csw = (fq ^ ((fr >> 1) & 3)) * 8;

  fx4 acc[8][4] = {};

  stage(0); stage(1); stage(2);          // 12 outstanding
  for (int kt = 0; kt < 32; ++kt) {
    if (kt < 29) stage(kt + 3);
    __builtin_amdgcn_sched_barrier(0);
    if (kt < 29)       asm volatile("s_waitcnt vmcnt(12)");
    else if (kt == 29) asm volatile("s_waitcnt vmcnt(8)");
    else if (kt == 30) asm volatile("s_waitcnt vmcnt(4)");
    else               asm volatile("s_waitcnt vmcnt(0)");
    __builtin_amdgcn_sched_barrier(0);
    __builtin_amdgcn_s_barrier();

    const short* slA = SM + (kt & 3) * 16384;
    const short* slB = slA + 8192;

    bfx8 af[8], bf[4];
#pragma unroll
    for (int rg = 0; rg < 8; ++rg)
      af[rg] = *(const bfx8*)&slA[(wr * 128 + rg * 16 + fr) * 32 + csw];
#pragma unroll
    for (int cg = 0; cg < 4; ++cg)
      bf[cg] = *(const bfx8*)&slB[(wn * 64 + cg * 16 + fr) * 32 + csw];

    __builtin_amdgcn_s_setprio(1);
#pragma unroll
    for (int rg = 0; rg < 8; ++rg)
#pragma unroll
      for (int cg = 0; cg < 4; ++cg)
        acc[rg][cg] = __builtin_amdgcn_mfma_f32_16x16x32_bf16(
            af[rg], bf[cg], acc[rg][cg], 0, 0, 0);
    __builtin_amdgcn_s_setprio(0);
    __builtin_amdgcn_sched_barrier(0);
    __builtin_amdgcn_s_barrier();
  }

  // ---- epilogue (R12, unchanged): 2 feature-half passes, LDS bounce ----
  const int b = t0b >> 9;
  if (z < 2) {
#pragma unroll
    for (int fp = 0; fp < 2; ++fp) {
      if (fp) __syncthreads();
      if (wr == fp) {
#pragma unroll
        for (int rg = 0; rg < 8; ++rg) {
          const int nloc = rg * 16 + fq * 4;
          const int nng = f0 + fp * 128 + nloc;
          const fx4 bb = *(const fx4*)&bias[nng];
#pragma unroll
          for (int cg = 0; cg < 4; ++cg) {
            const int token = wn * 64 + cg * 16 + fr;
            const int s = (t0b + token) & (Sq - 1);
            const fx4 pe = *(const fx4*)&pos[(size_t)s * Em + nng];
            const fx4 a = acc[rg][cg];
            bfx4 o = { f2bf(a[0] + bb[0] + pe[0]), f2bf(a[1] + bb[1] + pe[1]),
                       f2bf(a[2] + bb[2] + pe[2]), f2bf(a[3] + bb[3] + pe[3]) };
            *(bfx4*)&SM[token * 136 + nloc] = o;
          }
        }
      }
      __syncthreads();
#pragma unroll
      for (int it = 0; it < 8; ++it) {
        const int flat = it * 512 + t;
        const int token = flat >> 4, ch = flat & 15;
        bfx8 val = *(const bfx8*)&SM[token * 136 + ch * 8];
        const int nng = f0 + fp * 128 + ch * 8;
        const int h = nng >> 6, d = nng & 63;
        const int s = (t0b + token) & (Sq - 1);
        *(bfx8*)&dst[(((size_t)b * Hn + h) * Sq + s) * Dh + d] = val;
      }
    }
  } else {
#pragma unroll
    for (int fp = 0; fp < 2; ++fp) {
      if (fp) __syncthreads();
      if (wr == fp) {
#pragma unroll
        for (int rg = 0; rg < 8; ++rg) {
          const int nloc = rg * 16 + fq * 4;
          const int nng = f0 + fp * 128 + nloc;
          const fx4 bb = *(const fx4*)&bias[nng];
#pragma unroll
          for (int cg = 0; cg < 4; ++cg) {
            const int token = wn * 64 + cg * 16 + fr;
            const int s = (t0b + token) & (Sq - 1);
            const fx4 pe = *(const fx4*)&pos[(size_t)s * Em + nng];
            const fx4 a = acc[rg][cg];
#pragma unroll
            for (int i = 0; i < 4; ++i)
              SM[(nloc + i) * 264 + token] = f2bf(a[i] + bb[i] + pe[i]);
          }
        }
      }
      __syncthreads();
      const int s0 = t0b & (Sq - 1);
#pragma unroll
      for (int it = 0; it < 8; ++it) {
        const int flat = it * 512 + t;
        const int row = flat >> 5, ch = flat & 31;
        bfx8 val = *(const bfx8*)&SM[row * 264 + ch * 8];
        const int nng = f0 + fp * 128 + row;
        const int h = nng >> 6, d = nng & 63;
        *(bfx8*)&dst[(((size_t)b * Hn + h) * Dh + d) * Sq + s0 + ch * 8] = val;
      }
    }
  }
}

// ---------------- gemm_out (R7/R9 proven, unchanged) ----------------
constexpr int LDP = 136;

__global__ __launch_bounds__(256, 4) void gemm_out_bf16(
    const short* __restrict__ wv, const short* __restrict__ Wob,
    const float* __restrict__ bo, float* __restrict__ out)
{
  __shared__ short SMo[2 * 8192];
  short* As = SMo;
  short* Bs = SMo + 8192;

  const int m0 = blockIdx.x * 128;
  const int n0 = blockIdx.y * 128;
  const int t = threadIdx.x, lane = t & 63, wave = t >> 6;
  const int wr = wave >> 1, wc = wave & 1;
  const int fr = lane & 15, fq = lane >> 4;

  const int trow = t >> 3;
  const int scol = ((t & 7) ^ (trow & 7)) * 8;
  const short* gW = Wob + (size_t)(n0 + trow) * Em + scol;
  const short* gX = wv + (size_t)(m0 + trow) * Em + scol;
  short* lA = As + wave * 512;
  short* lB = Bs + wave * 512;

  const int sw0 = ((fq ^ (fr & 7)) * 8);
  const int sw1 = (((4 + fq) ^ (fr & 7)) * 8);

  fx4 acc[4][4] = {};

  for (int k0 = 0; k0 < Em; k0 += 64) {
#pragma unroll
    for (int r = 0; r < 4; ++r) {
      gld16(gW + (size_t)(32 * r) * Em + k0, lA + r * 2048);
      gld16(gX + (size_t)(32 * r) * Em + k0, lB + r * 2048);
    }
    __syncthreads();

#pragma unroll
    for (int ks = 0; ks < 2; ++ks) {
      const int sw = ks ? sw1 : sw0;
      bfx8 af[4], bf[4];
#pragma unroll
      for (int u = 0; u < 4; ++u)
        af[u] = *(const bfx8*)&As[(wr * 64 + u * 16 + fr) * 64 + sw];
#pragma unroll
      for (int v = 0; v < 4; ++v)
        bf[v] = *(const bfx8*)&Bs[(wc * 64 + v * 16 + fr) * 64 + sw];
#pragma unroll
      for (int u = 0; u < 4; ++u)
#pragma unroll
        for (int v = 0; v < 4; ++v)
          acc[u][v] = __builtin_amdgcn_mfma_f32_16x16x32_bf16(af[u], bf[v], acc[u][v], 0, 0, 0);
    }
    __syncthreads();
  }

#pragma unroll
  for (int u = 0; u < 4; ++u) {
    const int nn = n0 + wr * 64 + u * 16 + fq * 4;
    const fx4 bb = *(const fx4*)&bo[nn];
#pragma unroll
    for (int v = 0; v < 4; ++v) {
      const int m = m0 + wc * 64 + v * 16 + fr;
      fx4 val = acc[u][v];
      val[0] += bb[0]; val[1] += bb[1]; val[2] += bb[2]; val[3] += bb[3];
      *(fx4*)&out[(size_t)m * Em + nn] = val;
    }
  }
}

// ---------------- Attention (R12, unchanged) ----------------
constexpr int KVB = 64, LDK = 72;

__global__ __launch_bounds__(512) void attn_kernel(
    const short* __restrict__ qb, const short* __restrict__ kb,
    const short* __restrict__ vb, short* __restrict__ wv)
{
  __shared__ short Ks[KVB * LDK];
  __shared__ short Vt[Dh * LDK];
  __shared__ short Ps[8][16 * LDK];

  const int bh = blockIdx.x;
  const int qt = blockIdx.y;
  const int t = threadIdx.x, lane = t & 63, wave = t >> 6;
  const int fr = lane & 15, fq = lane >> 4;

  const size_t base = (size_t)bh * Sq * Dh;
  const int q0 = qt * 128 + wave * 16;

  bfx8 qf[2];
  {
    const short* qp = qb + base + (size_t)(q0 + fr) * Dh;
    qf[0] = *(const bfx8*)(qp + fq * 8);
    qf[1] = *(const bfx8*)(qp + 32 + fq * 8);
  }

  const int kr = t >> 3, kc = (t & 7) * 8;
  const short* kbp = kb + base + (size_t)kr * Dh + kc;
  const short* vbp = vb + base + (size_t)kr * Sq + kc;

  {
    bfx8 k0 = *(const bfx8*)kbp;
    bfx8 v0 = *(const bfx8*)vbp;
    *(bfx8*)&Ks[kr * LDK + kc] = k0;
    *(bfx8*)&Vt[kr * LDK + kc] = v0;
  }
  __syncthreads();

  float mrow[4] = { -1e30f, -1e30f, -1e30f, -1e30f };
  float lrow[4] = { 0.f, 0.f, 0.f, 0.f };
  fx4 oacc[4] = {};

  for (int kv0 = 0; kv0 < Sq; kv0 += KVB) {
    const bool more = (kv0 + KVB) < Sq;
    bfx8 nk0, nv0;
    if (more) {
      nk0 = *(const bfx8*)(kbp + (size_t)(kv0 + KVB) * Dh);
      nv0 = *(const bfx8*)(vbp + kv0 + KVB);
    }

    fx4 sa[4] = {};
    __builtin_amdgcn_s_setprio(1);
#pragma unroll
    for (int nf = 0; nf < 4; ++nf) {
#pragma unroll
      for (int ks = 0; ks < 2; ++ks) {
        bfx8 kf = *(const bfx8*)&Ks[(nf * 16 + fr) * LDK + ks * 32 + fq * 8];
        sa[nf] = __builtin_amdgcn_mfma_f32_16x16x32_bf16(qf[ks], kf, sa[nf], 0, 0, 0);
      }
    }
    __builtin_amdgcn_s_setprio(0);

#pragma unroll
    for (int i = 0; i < 4; ++i) {
      float mx = fmaxf(fmaxf(sa[0][i], sa[1][i]), fmaxf(sa[2][i], sa[3][i]));
      mx = fmaxf(mx, __shfl_xor(mx, 1));
      mx = fmaxf(mx, __shfl_xor(mx, 2));
      mx = fmaxf(mx, __shfl_xor(mx, 4));
      mx = fmaxf(mx, __shfl_xor(mx, 8));
      mx *= 0.125f;
      if (mx > mrow[i] + 8.f) {
        const float alpha = __expf(mrow[i] - mx);
        mrow[i] = mx;
        lrow[i] *= alpha;
#pragma unroll
        for (int df = 0; df < 4; ++df) oacc[df][i] *= alpha;
      }
      float rs = 0.f;
#pragma unroll
      for (int nf = 0; nf < 4; ++nf) {
        const float p = __expf(sa[nf][i] * 0.125f - mrow[i]);
        rs += p;
        Ps[wave][(fq * 4 + i) * LDK + nf * 16 + fr] = f2bf(p);
      }
      rs += __shfl_xor(rs, 1);
      rs += __shfl_xor(rs, 2);
      rs += __shfl_xor(rs, 4);
      rs += __shfl_xor(rs, 8);
      lrow[i] += rs;
    }

    bfx8 pf[2];
    pf[0] = *(const bfx8*)&Ps[wave][fr * LDK + fq * 8];
    pf[1] = *(const bfx8*)&Ps[wave][fr * LDK + 32 + fq * 8];
    __builtin_amdgcn_s_setprio(1);
#pragma unroll
    for (int df = 0; df < 4; ++df) {
#pragma unroll
      for (int ks = 0; ks < 2; ++ks) {
        bfx8 vf = *(const bfx8*)&Vt[(df * 16 + fr) * LDK + ks * 32 + fq * 8];
        oacc[df] = __builtin_amdgcn_mfma_f32_16x16x32_bf16(pf[ks], vf, oacc[df], 0, 0, 0);
      }
    }
    __builtin_amdgcn_s_setprio(0);
    __syncthreads();

    if (more) {
      *(bfx8*)&Ks[kr * LDK + kc] = nk0;
      *(bfx8*)&Vt[kr * LDK + kc] = nv0;
      __syncthreads();
    }
  }

  const int b = bh >> 4, h = bh & 15;
#pragma unroll
  for (int df = 0; df < 4; ++df) {
    const int d = df * 16 + fr;
#pragma unroll
    for (int i = 0; i < 4; ++i) {
      const int qrow = q0 + fq * 4 + i;
      const float o = oacc[df][i] / lrow[i];
      wv[((size_t)b * Sq + qrow) * Em + h * Dh + d] = f2bf(o);
    }
  }
}

extern "C" void kernel_launch(void* const* d_in, const int* in_sizes, int n_in,
                              void* d_out, int out_size, void* d_ws, size_t ws_size,
                              hipStream_t stream) {
  (void)in_sizes; (void)n_in; (void)out_size; (void)ws_size;
  const float* query = (const float*)d_in[0];
  const float* key   = (const float*)d_in[1];
  const float* value = (const float*)d_in[2];
  const float* Wq = (const float*)d_in[3];
  const float* bq = (const float*)d_in[4];
  const float* Wk = (const float*)d_in[5];
  const float* bk = (const float*)d_in[6];
  const float* Wv = (const float*)d_in[7];
  const float* bv = (const float*)d_in[8];
  const float* Wo = (const float*)d_in[9];
  const float* bo = (const float*)d_in[10];
  const float* pos = (const float*)d_in[11];

  short* qx = (short*)d_ws;
  short* kx = qx + NE;
  short* vx = kx + NE;
  short* Wqb = vx + NE;
  short* Wkb = Wqb + WE;
  short* Wvb = Wkb + WE;
  short* Wob = Wvb + WE;
  short* qb = Wob + WE;
  short* wv = qx;                 // alias: qx dead after gemm_qkv
  short* kb = (short*)d_out;      // d_out scratch, overwritten by gemm_out
  short* vb = kb + NE;            // [B,H,Dh,S]

  convert_kernel<<<dim3(8192), 256, 0, stream>>>(
      query, key, value, Wq, Wk, Wv, Wo, qx, kx, vx, Wqb, Wkb, Wvb, Wob);
  gemm_qkv_bf16<<<dim3(Mrows / 256, Em / 256, 3), 512, 0, stream>>>(
      qx, kx, vx, Wqb, Wkb, Wvb, bq, bk, bv, pos, qb, kb, vb);
  attn_kernel<<<dim3(Bz * Hn, Sq / 128), 512, 0, stream>>>(qb, kb, vb, wv);
  gemm_out_bf16<<<dim3(Mrows / 128, Em / 128), 256, 0, stream>>>(
      wv, Wob, bo, (float*)d_out);
}

// Round 14
// 106.292 us; speedup vs baseline: 1.0517x; 1.0517x over previous
//
#include <hip/hip_runtime.h>
#include <hip/hip_bf16.h>

typedef __attribute__((ext_vector_type(8))) short bfx8;
typedef __attribute__((ext_vector_type(4))) short bfx4;
typedef __attribute__((ext_vector_type(4))) float fx4;

static __device__ __forceinline__ short f2bf(float f) {
  union { float f; unsigned u; } v; v.f = f;
  unsigned r = v.u + 0x7fffu + ((v.u >> 16) & 1u);
  return (short)(r >> 16);
}

static __device__ __forceinline__ void gld16(const void* g, void* l) {
  __builtin_amdgcn_global_load_lds(
      (const __attribute__((address_space(1))) void*)g,
      (__attribute__((address_space(3))) void*)l, 16, 0, 0);
}

constexpr int Bz = 8, Sq = 512, Em = 1024, Hn = 16, Dh = 64;
constexpr int Mrows = Bz * Sq;             // 4096
constexpr size_t NE = (size_t)Mrows * Em;  // 4,194,304
constexpr size_t WE = (size_t)Em * Em;     // 1,048,576
constexpr int NT = Em / 64;                // 16 K-tiles

// ---------------- f32 -> bf16 pre-convert (unchanged) ----------------
__global__ __launch_bounds__(256) void convert_kernel(
    const float* __restrict__ q, const float* __restrict__ k,
    const float* __restrict__ v,
    const float* __restrict__ Wq, const float* __restrict__ Wk,
    const float* __restrict__ Wv, const float* __restrict__ Wo,
    short* __restrict__ qx, short* __restrict__ kx, short* __restrict__ vx,
    short* __restrict__ wqb, short* __restrict__ wkb,
    short* __restrict__ wvb, short* __restrict__ wob)
{
  const size_t c = (size_t)blockIdx.x * 256 + threadIdx.x;
  constexpr size_t CI = NE / 8;
  constexpr size_t CW = WE / 8;
  const float* src; short* dst; size_t off;
  if (c < 3 * CI) {
    const int sgi = (int)(c / CI);
    src = sgi == 0 ? q : sgi == 1 ? k : v;
    dst = sgi == 0 ? qx : sgi == 1 ? kx : vx;
    off = (c - (size_t)sgi * CI) * 8;
  } else {
    const size_t w = c - 3 * CI;
    const int sgi = (int)(w / CW);
    src = sgi == 0 ? Wq : sgi == 1 ? Wk : sgi == 2 ? Wv : Wo;
    dst = sgi == 0 ? wqb : sgi == 1 ? wkb : sgi == 2 ? wvb : wob;
    off = (w - (size_t)sgi * CW) * 8;
  }
  fx4 a = *(const fx4*)(src + off);
  fx4 b = *(const fx4*)(src + off + 4);
  bfx8 o = { f2bf(a[0]), f2bf(a[1]), f2bf(a[2]), f2bf(a[3]),
             f2bf(b[0]), f2bf(b[1]), f2bf(b[2]), f2bf(b[3]) };
  *(bfx8*)(dst + off) = o;
}

// ---------------- gemm_qkv: 256x256, 8 waves, 4-phase/K-tile (exact R12) ----------------
__global__ __launch_bounds__(512, 2) void gemm_qkv_bf16(
    const short* __restrict__ qx, const short* __restrict__ kx,
    const short* __restrict__ vx,
    const short* __restrict__ Wqb, const short* __restrict__ Wkb,
    const short* __restrict__ Wvb,
    const float* __restrict__ bq, const float* __restrict__ bk,
    const float* __restrict__ bv,
    const float* __restrict__ pos,
    short* __restrict__ qb, short* __restrict__ kb, short* __restrict__ vb)
{
  __shared__ short SM[65536];   // 128KB

  const int z = blockIdx.z;
  const short* X = (z == 0) ? qx : (z == 1) ? kx : vx;
  const short* W = (z == 0) ? Wqb : (z == 1) ? Wkb : Wvb;
  const float* bias = (z == 0) ? bq : (z == 1) ? bk : bv;
  short* dst = (z == 0) ? qb : (z == 1) ? kb : vb;

  const int t0b = blockIdx.x * 256;
  const int f0 = blockIdx.y * 256;
  const int t = threadIdx.x, lane = t & 63, wave = t >> 6;
  const int wr = wave >> 2;
  const int wn = wave & 3;
  const int fr = lane & 15, fq = lane >> 4;

  const int srow = t >> 3;
  const int scc = (t & 7) ^ (srow & 7);
  const int sdst = wave * 512;

  const int sw0 = (fq ^ (fr & 7)) * 8;
  const int sw1 = ((4 + fq) ^ (fr & 7)) * 8;

  auto stageA = [&](int hh, int ktn, int pn) {
    const short* s = W + (size_t)(f0 + hh * 128 + srow) * Em + ktn * 64 + scc * 8;
    short* d = SM + pn * 32768 + hh * 8192 + sdst;
    gld16(s, d);
    gld16(s + (size_t)64 * Em, d + 4096);
  };
  auto stageB = [&](int hh, int ktn, int pn) {
    const short* s = X + (size_t)(t0b + hh * 128 + srow) * Em + ktn * 64 + scc * 8;
    short* d = SM + pn * 32768 + 16384 + hh * 8192 + sdst;
    gld16(s, d);
    gld16(s + (size_t)64 * Em, d + 4096);
  };

  fx4 acc[8][4] = {};

  stageA(0, 0, 0); stageA(1, 0, 0); stageB(0, 0, 0); stageB(1, 0, 0);
  __builtin_amdgcn_sched_barrier(0);
  asm volatile("s_waitcnt vmcnt(0)");
  __builtin_amdgcn_sched_barrier(0);
  __builtin_amdgcn_s_barrier();

  for (int kt = 0; kt < NT; ++kt) {
    const int p = kt & 1, pn = p ^ 1;
    const bool pre = (kt + 1 < NT);
    const short* Ab = SM + p * 32768 + wr * 8192;
    const short* Bb = SM + p * 32768 + 16384 + (wn >> 1) * 8192 + (wn & 1) * 4096;

    bfx8 bf[4][2];
#pragma unroll
    for (int q = 0; q < 4; ++q) {
      if (q == 0) {
#pragma unroll
        for (int cg = 0; cg < 4; ++cg) {
          bf[cg][0] = *(const bfx8*)&Bb[(cg * 16 + fr) * 64 + sw0];
          bf[cg][1] = *(const bfx8*)&Bb[(cg * 16 + fr) * 64 + sw1];
        }
      }
      bfx8 af[2][2];
#pragma unroll
      for (int rr2 = 0; rr2 < 2; ++rr2) {
        const int row = (q * 2 + rr2) * 16 + fr;
        af[rr2][0] = *(const bfx8*)&Ab[row * 64 + sw0];
        af[rr2][1] = *(const bfx8*)&Ab[row * 64 + sw1];
      }
      if (q == 0 && pre) { stageA(0, kt + 1, pn); stageA(1, kt + 1, pn); }
      if (q == 1 && pre) { stageB(0, kt + 1, pn); stageB(1, kt + 1, pn); }

      __builtin_amdgcn_sched_barrier(0);
      __builtin_amdgcn_s_barrier();
      __builtin_amdgcn_sched_barrier(0);

      __builtin_amdgcn_s_setprio(1);
#pragma unroll
      for (int rr2 = 0; rr2 < 2; ++rr2)
#pragma unroll
        for (int cg = 0; cg < 4; ++cg) {
          acc[q * 2 + rr2][cg] = __builtin_amdgcn_mfma_f32_16x16x32_bf16(
              af[rr2][0], bf[cg][0], acc[q * 2 + rr2][cg], 0, 0, 0);
          acc[q * 2 + rr2][cg] = __builtin_amdgcn_mfma_f32_16x16x32_bf16(
              af[rr2][1], bf[cg][1], acc[q * 2 + rr2][cg], 0, 0, 0);
        }
      __builtin_amdgcn_s_setprio(0);
      __builtin_amdgcn_sched_barrier(0);

      if (q == 3 && pre) {
        asm volatile("s_waitcnt vmcnt(0)");
        __builtin_amdgcn_sched_barrier(0);
      }
      __builtin_amdgcn_s_barrier();
    }
  }

  // ---- epilogue (unchanged) ----
  const int b = t0b >> 9;
  if (z < 2) {
#pragma unroll
    for (int fp = 0; fp < 2; ++fp) {
      if (fp) __syncthreads();
      if (wr == fp) {
#pragma unroll
        for (int rg = 0; rg < 8; ++rg) {
          const int nloc = rg * 16 + fq * 4;
          const int nng = f0 + fp * 128 + nloc;
          const fx4 bb = *(const fx4*)&bias[nng];
#pragma unroll
          for (int cg = 0; cg < 4; ++cg) {
            const int token = wn * 64 + cg * 16 + fr;
            const int s = (t0b + token) & (Sq - 1);
            const fx4 pe = *(const fx4*)&pos[(size_t)s * Em + nng];
            const fx4 a = acc[rg][cg];
            bfx4 o = { f2bf(a[0] + bb[0] + pe[0]), f2bf(a[1] + bb[1] + pe[1]),
                       f2bf(a[2] + bb[2] + pe[2]), f2bf(a[3] + bb[3] + pe[3]) };
            *(bfx4*)&SM[token * 136 + nloc] = o;
          }
        }
      }
      __syncthreads();
#pragma unroll
      for (int it = 0; it < 8; ++it) {
        const int flat = it * 512 + t;
        const int token = flat >> 4, ch = flat & 15;
        bfx8 val = *(const bfx8*)&SM[token * 136 + ch * 8];
        const int nng = f0 + fp * 128 + ch * 8;
        const int h = nng >> 6, d = nng & 63;
        const int s = (t0b + token) & (Sq - 1);
        *(bfx8*)&dst[(((size_t)b * Hn + h) * Sq + s) * Dh + d] = val;
      }
    }
  } else {
#pragma unroll
    for (int fp = 0; fp < 2; ++fp) {
      if (fp) __syncthreads();
      if (wr == fp) {
#pragma unroll
        for (int rg = 0; rg < 8; ++rg) {
          const int nloc = rg * 16 + fq * 4;
          const int nng = f0 + fp * 128 + nloc;
          const fx4 bb = *(const fx4*)&bias[nng];
#pragma unroll
          for (int cg = 0; cg < 4; ++cg) {
            const int token = wn * 64 + cg * 16 + fr;
            const int s = (t0b + token) & (Sq - 1);
            const fx4 pe = *(const fx4*)&pos[(size_t)s * Em + nng];
            const fx4 a = acc[rg][cg];
#pragma unroll
            for (int i = 0; i < 4; ++i)
              SM[(nloc + i) * 264 + token] = f2bf(a[i] + bb[i] + pe[i]);
          }
        }
      }
      __syncthreads();
      const int s0 = t0b & (Sq - 1);
#pragma unroll
      for (int it = 0; it < 8; ++it) {
        const int flat = it * 512 + t;
        const int row = flat >> 5, ch = flat & 31;
        bfx8 val = *(const bfx8*)&SM[row * 264 + ch * 8];
        const int nng = f0 + fp * 128 + row;
        const int h = nng >> 6, d = nng & 63;
        *(bfx8*)&dst[(((size_t)b * Hn + h) * Dh + d) * Sq + s0 + ch * 8] = val;
      }
    }
  }
}

// ---------------- gemm_out: 64x128 tile, 512 blocks (2/CU), R7 loop ----------------
// C^T orientation: A=Wo rows (128 feats), B=wv rows (64 tokens). 4 waves:
// wr=feat half (64), wc=token half (32). acc[4][2]. BK=64, 16 steps,
// 6 gld16/thread/step, single-buffered (proven R7 loop), XOR swizzle both-sides.
__global__ __launch_bounds__(256, 4) void gemm_out_bf16(
    const short* __restrict__ wv, const short* __restrict__ Wob,
    const float* __restrict__ bo, float* __restrict__ out)
{
  __shared__ short As[128 * 64];   // 16KB
  __shared__ short Bs[64 * 64];    // 8KB

  const int m0 = blockIdx.x * 64;    // tokens (fast axis -> XCD locality)
  const int n0 = blockIdx.y * 128;   // features
  const int t = threadIdx.x, lane = t & 63, wave = t >> 6;
  const int wr = wave >> 1, wc = wave & 1;
  const int fr = lane & 15, fq = lane >> 4;

  // staging: group g -> row g*32 + (t>>3), source col chunk (t&7)^(row&7)
  const int trow = t >> 3;
  const int scol = ((t & 7) ^ (trow & 7)) * 8;
  const short* gW = Wob + (size_t)(n0 + trow) * Em + scol;
  const short* gX = wv + (size_t)(m0 + trow) * Em + scol;
  const int lofs = wave * 512;

  const int sw0 = ((fq ^ (fr & 7)) * 8);
  const int sw1 = (((4 + fq) ^ (fr & 7)) * 8);

  fx4 acc[4][2] = {};

  for (int k0 = 0; k0 < Em; k0 += 64) {
#pragma unroll
    for (int g = 0; g < 4; ++g)
      gld16(gW + (size_t)(32 * g) * Em + k0, As + g * 2048 + lofs);
#pragma unroll
    for (int g = 0; g < 2; ++g)
      gld16(gX + (size_t)(32 * g) * Em + k0, Bs + g * 2048 + lofs);
    __syncthreads();

#pragma unroll
    for (int ks = 0; ks < 2; ++ks) {
      const int sw = ks ? sw1 : sw0;
      bfx8 af[4], bf[2];
#pragma unroll
      for (int u = 0; u < 4; ++u)
        af[u] = *(const bfx8*)&As[(wr * 64 + u * 16 + fr) * 64 + sw];
#pragma unroll
      for (int v = 0; v < 2; ++v)
        bf[v] = *(const bfx8*)&Bs[(wc * 32 + v * 16 + fr) * 64 + sw];
#pragma unroll
      for (int u = 0; u < 4; ++u)
#pragma unroll
        for (int v = 0; v < 2; ++v)
          acc[u][v] = __builtin_amdgcn_mfma_f32_16x16x32_bf16(af[u], bf[v], acc[u][v], 0, 0, 0);
    }
    __syncthreads();
  }

#pragma unroll
  for (int u = 0; u < 4; ++u) {
    const int nn = n0 + wr * 64 + u * 16 + fq * 4;
    const fx4 bb = *(const fx4*)&bo[nn];
#pragma unroll
    for (int v = 0; v < 2; ++v) {
      const int m = m0 + wc * 32 + v * 16 + fr;
      fx4 val = acc[u][v];
      val[0] += bb[0]; val[1] += bb[1]; val[2] += bb[2]; val[3] += bb[3];
      *(fx4*)&out[(size_t)m * Em + nn] = val;
    }
  }
}

// ---------------- Attention (R12, unchanged) ----------------
constexpr int KVB = 64, LDK = 72;

__global__ __launch_bounds__(512) void attn_kernel(
    const short* __restrict__ qb, const short* __restrict__ kb,
    const short* __restrict__ vb, short* __restrict__ wv)
{
  __shared__ short Ks[KVB * LDK];
  __shared__ short Vt[Dh * LDK];
  __shared__ short Ps[8][16 * LDK];

  const int bh = blockIdx.x;
  const int qt = blockIdx.y;
  const int t = threadIdx.x, lane = t & 63, wave = t >> 6;
  const int fr = lane & 15, fq = lane >> 4;

  const size_t base = (size_t)bh * Sq * Dh;
  const int q0 = qt * 128 + wave * 16;

  bfx8 qf[2];
  {
    const short* qp = qb + base + (size_t)(q0 + fr) * Dh;
    qf[0] = *(const bfx8*)(qp + fq * 8);
    qf[1] = *(const bfx8*)(qp + 32 + fq * 8);
  }

  const int kr = t >> 3, kc = (t & 7) * 8;
  const short* kbp = kb + base + (size_t)kr * Dh + kc;
  const short* vbp = vb + base + (size_t)kr * Sq + kc;

  {
    bfx8 k0 = *(const bfx8*)kbp;
    bfx8 v0 = *(const bfx8*)vbp;
    *(bfx8*)&Ks[kr * LDK + kc] = k0;
    *(bfx8*)&Vt[kr * LDK + kc] = v0;
  }
  __syncthreads();

  float mrow[4] = { -1e30f, -1e30f, -1e30f, -1e30f };
  float lrow[4] = { 0.f, 0.f, 0.f, 0.f };
  fx4 oacc[4] = {};

  for (int kv0 = 0; kv0 < Sq; kv0 += KVB) {
    const bool more = (kv0 + KVB) < Sq;
    bfx8 nk0, nv0;
    if (more) {
      nk0 = *(const bfx8*)(kbp + (size_t)(kv0 + KVB) * Dh);
      nv0 = *(const bfx8*)(vbp + kv0 + KVB);
    }

    fx4 sa[4] = {};
    __builtin_amdgcn_s_setprio(1);
#pragma unroll
    for (int nf = 0; nf < 4; ++nf) {
#pragma unroll
      for (int ks = 0; ks < 2; ++ks) {
        bfx8 kf = *(const bfx8*)&Ks[(nf * 16 + fr) * LDK + ks * 32 + fq * 8];
        sa[nf] = __builtin_amdgcn_mfma_f32_16x16x32_bf16(qf[ks], kf, sa[nf], 0, 0, 0);
      }
    }
    __builtin_amdgcn_s_setprio(0);

#pragma unroll
    for (int i = 0; i < 4; ++i) {
      float mx = fmaxf(fmaxf(sa[0][i], sa[1][i]), fmaxf(sa[2][i], sa[3][i]));
      mx = fmaxf(mx, __shfl_xor(mx, 1));
      mx = fmaxf(mx, __shfl_xor(mx, 2));
      mx = fmaxf(mx, __shfl_xor(mx, 4));
      mx = fmaxf(mx, __shfl_xor(mx, 8));
      mx *= 0.125f;
      if (mx > mrow[i] + 8.f) {
        const float alpha = __expf(mrow[i] - mx);
        mrow[i] = mx;
        lrow[i] *= alpha;
#pragma unroll
        for (int df = 0; df < 4; ++df) oacc[df][i] *= alpha;
      }
      float rs = 0.f;
#pragma unroll
      for (int nf = 0; nf < 4; ++nf) {
        const float p = __expf(sa[nf][i] * 0.125f - mrow[i]);
        rs += p;
        Ps[wave][(fq * 4 + i) * LDK + nf * 16 + fr] = f2bf(p);
      }
      rs += __shfl_xor(rs, 1);
      rs += __shfl_xor(rs, 2);
      rs += __shfl_xor(rs, 4);
      rs += __shfl_xor(rs, 8);
      lrow[i] += rs;
    }

    bfx8 pf[2];
    pf[0] = *(const bfx8*)&Ps[wave][fr * LDK + fq * 8];
    pf[1] = *(const bfx8*)&Ps[wave][fr * LDK + 32 + fq * 8];
    __builtin_amdgcn_s_setprio(1);
#pragma unroll
    for (int df = 0; df < 4; ++df) {
#pragma unroll
      for (int ks = 0; ks < 2; ++ks) {
        bfx8 vf = *(const bfx8*)&Vt[(df * 16 + fr) * LDK + ks * 32 + fq * 8];
        oacc[df] = __builtin_amdgcn_mfma_f32_16x16x32_bf16(pf[ks], vf, oacc[df], 0, 0, 0);
      }
    }
    __builtin_amdgcn_s_setprio(0);
    __syncthreads();

    if (more) {
      *(bfx8*)&Ks[kr * LDK + kc] = nk0;
      *(bfx8*)&Vt[kr * LDK + kc] = nv0;
      __syncthreads();
    }
  }

  const int b = bh >> 4, h = bh & 15;
#pragma unroll
  for (int df = 0; df < 4; ++df) {
    const int d = df * 16 + fr;
#pragma unroll
    for (int i = 0; i < 4; ++i) {
      const int qrow = q0 + fq * 4 + i;
      const float o = oacc[df][i] / lrow[i];
      wv[((size_t)b * Sq + qrow) * Em + h * Dh + d] = f2bf(o);
    }
  }
}

extern "C" void kernel_launch(void* const* d_in, const int* in_sizes, int n_in,
                              void* d_out, int out_size, void* d_ws, size_t ws_size,
                              hipStream_t stream) {
  (void)in_sizes; (void)n_in; (void)out_size; (void)ws_size;
  const float* query = (const float*)d_in[0];
  const float* key   = (const float*)d_in[1];
  const float* value = (const float*)d_in[2];
  const float* Wq = (const float*)d_in[3];
  const float* bq = (const float*)d_in[4];
  const float* Wk = (const float*)d_in[5];
  const float* bk = (const float*)d_in[6];
  const float* Wv = (const float*)d_in[7];
  const float* bv = (const float*)d_in[8];
  const float* Wo = (const float*)d_in[9];
  const float* bo = (const float*)d_in[10];
  const float* pos = (const float*)d_in[11];

  short* qx = (short*)d_ws;
  short* kx = qx + NE;
  short* vx = kx + NE;
  short* Wqb = vx + NE;
  short* Wkb = Wqb + WE;
  short* Wvb = Wkb + WE;
  short* Wob = Wvb + WE;
  short* qb = Wob + WE;
  short* wv = qx;                 // alias: qx dead after gemm_qkv
  short* kb = (short*)d_out;      // d_out scratch, overwritten by gemm_out
  short* vb = kb + NE;            // [B,H,Dh,S]

  convert_kernel<<<dim3(8192), 256, 0, stream>>>(
      query, key, value, Wq, Wk, Wv, Wo, qx, kx, vx, Wqb, Wkb, Wvb, Wob);
  gemm_qkv_bf16<<<dim3(Mrows / 256, Em / 256, 3), 512, 0, stream>>>(
      qx, kx, vx, Wqb, Wkb, Wvb, bq, bk, bv, pos, qb, kb, vb);
  attn_kernel<<<dim3(Bz * Hn, Sq / 128), 512, 0, stream>>>(qb, kb, vb, wv);
  gemm_out_bf16<<<dim3(Mrows / 64, Em / 128), 256, 0, stream>>>(
      wv, Wob, bo, (float*)d_out);
}

// Round 15
// 103.340 us; speedup vs baseline: 1.0817x; 1.0286x over previous
//
#include <hip/hip_runtime.h>
#include <hip/hip_bf16.h>

typedef __attribute__((ext_vector_type(8))) short bfx8;
typedef __attribute__((ext_vector_type(4))) short bfx4;
typedef __attribute__((ext_vector_type(4))) float fx4;

static __device__ __forceinline__ short f2bf(float f) {
  union { float f; unsigned u; } v; v.f = f;
  unsigned r = v.u + 0x7fffu + ((v.u >> 16) & 1u);
  return (short)(r >> 16);
}

static __device__ __forceinline__ void gld16(const void* g, void* l) {
  __builtin_amdgcn_global_load_lds(
      (const __attribute__((address_space(1))) void*)g,
      (__attribute__((address_space(3))) void*)l, 16, 0, 0);
}

constexpr int Bz = 8, Sq = 512, Em = 1024, Hn = 16, Dh = 64;
constexpr int Mrows = Bz * Sq;             // 4096
constexpr size_t NE = (size_t)Mrows * Em;  // 4,194,304
constexpr size_t WE = (size_t)Em * Em;     // 1,048,576

// ---------------- f32 -> bf16 pre-convert (unchanged) ----------------
__global__ __launch_bounds__(256) void convert_kernel(
    const float* __restrict__ q, const float* __restrict__ k,
    const float* __restrict__ v,
    const float* __restrict__ Wq, const float* __restrict__ Wk,
    const float* __restrict__ Wv, const float* __restrict__ Wo,
    short* __restrict__ qx, short* __restrict__ kx, short* __restrict__ vx,
    short* __restrict__ wqb, short* __restrict__ wkb,
    short* __restrict__ wvb, short* __restrict__ wob)
{
  const size_t c = (size_t)blockIdx.x * 256 + threadIdx.x;
  constexpr size_t CI = NE / 8;
  constexpr size_t CW = WE / 8;
  const float* src; short* dst; size_t off;
  if (c < 3 * CI) {
    const int sgi = (int)(c / CI);
    src = sgi == 0 ? q : sgi == 1 ? k : v;
    dst = sgi == 0 ? qx : sgi == 1 ? kx : vx;
    off = (c - (size_t)sgi * CI) * 8;
  } else {
    const size_t w = c - 3 * CI;
    const int sgi = (int)(w / CW);
    src = sgi == 0 ? Wq : sgi == 1 ? Wk : sgi == 2 ? Wv : Wo;
    dst = sgi == 0 ? wqb : sgi == 1 ? wkb : sgi == 2 ? wvb : wob;
    off = (w - (size_t)sgi * CW) * 8;
  }
  fx4 a = *(const fx4*)(src + off);
  fx4 b = *(const fx4*)(src + off + 4);
  bfx8 o = { f2bf(a[0]), f2bf(a[1]), f2bf(a[2]), f2bf(a[3]),
             f2bf(b[0]), f2bf(b[1]), f2bf(b[2]), f2bf(b[3]) };
  *(bfx8*)(dst + off) = o;
}

// ---------------- gemm_qkv: 256 tokens x 128 features, BK=32, dbuf 48KB ----------------
// 384 blocks -> 2 blocks/CU co-resident (TLP hides the per-tile drain; R7/R14
// occupancy mechanism). 8 waves: wf=feature half (64), wt=token quarter (64);
// per-wave acc[4][4], 16 MFMA/K-step. One barrier + one vmcnt per K-step.
// Swizzle: LDS[r][c] = src[r][c^((r>>1)&3)]; read chunk fq^((fr>>1)&3).
__global__ __launch_bounds__(512, 4) void gemm_qkv_bf16(
    const short* __restrict__ qx, const short* __restrict__ kx,
    const short* __restrict__ vx,
    const short* __restrict__ Wqb, const short* __restrict__ Wkb,
    const short* __restrict__ Wvb,
    const float* __restrict__ bq, const float* __restrict__ bk,
    const float* __restrict__ bv,
    const float* __restrict__ pos,
    short* __restrict__ qb, short* __restrict__ kb, short* __restrict__ vb)
{
  __shared__ short SM[24576];   // 48KB: 2 slots x (A[128][32] + B[256][32])

  const int z = blockIdx.z;
  const short* X = (z == 0) ? qx : (z == 1) ? kx : vx;
  const short* W = (z == 0) ? Wqb : (z == 1) ? Wkb : Wvb;
  const float* bias = (z == 0) ? bq : (z == 1) ? bk : bv;
  short* dst = (z == 0) ? qb : (z == 1) ? kb : vb;

  const int t0b = blockIdx.x * 256;   // tokens (fast axis -> XCD locality)
  const int f0 = blockIdx.y * 128;    // features
  const int t = threadIdx.x, lane = t & 63, wave = t >> 6;
  const int wf = wave & 1;            // feature half (64)
  const int wt = wave >> 1;           // token quarter (64)
  const int fr = lane & 15, fq = lane >> 4;

  // staging: thread t -> row t>>2, LDS chunk t (linear), src chunk (t&3)^((t>>3)&3)
  const int srow = t >> 2;
  const int scol = ((t & 3) ^ ((t >> 3) & 3)) * 8;
  const short* gA = W + (size_t)(f0 + srow) * Em + scol;
  const short* gB = X + (size_t)(t0b + srow) * Em + scol;
  const int ldst = wave * 512;

  auto stage = [&](int ktn, int s) {
    short* base = SM + s * 12288;
    const int ko = ktn * 32;
    gld16(gA + ko, base + ldst);                                 // A (128 rows)
    gld16(gB + ko, base + 4096 + ldst);                          // B rows 0..127
    gld16(gB + (size_t)128 * Em + ko, base + 8192 + ldst);       // B rows 128..255
  };

  const int csw = (fq ^ ((fr >> 1) & 3)) * 8;

  fx4 acc[4][4] = {};

  stage(0, 0);
  __builtin_amdgcn_sched_barrier(0);
  asm volatile("s_waitcnt vmcnt(0)");
  __builtin_amdgcn_sched_barrier(0);
  __builtin_amdgcn_s_barrier();

  for (int kt = 0; kt < 32; ++kt) {
    const int s = kt & 1;
    const short* bA = SM + s * 12288;
    const short* bB = bA + 4096;
    const bool pre = (kt + 1 < 32);
    if (pre) stage(kt + 1, s ^ 1);
    __builtin_amdgcn_sched_barrier(0);

    bfx8 af[4], bf[4];
#pragma unroll
    for (int u = 0; u < 4; ++u)
      af[u] = *(const bfx8*)&bA[(wf * 64 + u * 16 + fr) * 32 + csw];
#pragma unroll
    for (int v = 0; v < 4; ++v)
      bf[v] = *(const bfx8*)&bB[(wt * 64 + v * 16 + fr) * 32 + csw];

    __builtin_amdgcn_s_setprio(1);
#pragma unroll
    for (int u = 0; u < 4; ++u)
#pragma unroll
      for (int v = 0; v < 4; ++v)
        acc[u][v] = __builtin_amdgcn_mfma_f32_16x16x32_bf16(af[u], bf[v], acc[u][v], 0, 0, 0);
    __builtin_amdgcn_s_setprio(0);
    __builtin_amdgcn_sched_barrier(0);

    if (pre) asm volatile("s_waitcnt vmcnt(0)");
    __builtin_amdgcn_sched_barrier(0);
    __builtin_amdgcn_s_barrier();
  }

  // ---- epilogue: +bias+pe, 2-pass LDS bounce, coalesced stores ----
  const int b = t0b >> 9;
  if (z < 2) {
    // 2 passes over token halves: C-tile [128t][128f+pad]
#pragma unroll
    for (int p = 0; p < 2; ++p) {
      if (p) __syncthreads();
      if ((wt >> 1) == p) {
#pragma unroll
        for (int u = 0; u < 4; ++u) {
          const int nloc = wf * 64 + u * 16 + fq * 4;
          const int nng = f0 + nloc;
          const fx4 bb = *(const fx4*)&bias[nng];
#pragma unroll
          for (int v = 0; v < 4; ++v) {
            const int token = wt * 64 + v * 16 + fr;       // 0..255
            const int tl = token - p * 128;                // 0..127
            const int s = (t0b + token) & (Sq - 1);
            const fx4 pe = *(const fx4*)&pos[(size_t)s * Em + nng];
            const fx4 a = acc[u][v];
            bfx4 o = { f2bf(a[0] + bb[0] + pe[0]), f2bf(a[1] + bb[1] + pe[1]),
                       f2bf(a[2] + bb[2] + pe[2]), f2bf(a[3] + bb[3] + pe[3]) };
            *(bfx4*)&SM[tl * 136 + nloc] = o;
          }
        }
      }
      __syncthreads();
#pragma unroll
      for (int it = 0; it < 4; ++it) {
        const int flat = it * 512 + t;
        const int tl = flat >> 4, ch = flat & 15;
        bfx8 val = *(const bfx8*)&SM[tl * 136 + ch * 8];
        const int nng = f0 + ch * 8;
        const int h = nng >> 6, d = nng & 63;
        const int s = (t0b + p * 128 + tl) & (Sq - 1);
        *(bfx8*)&dst[(((size_t)b * Hn + h) * Sq + s) * Dh + d] = val;
      }
    }
  } else {
    // V^T [B,H,Dh,S]: 2 passes over feature halves of 64; C-tile [64f][256t+swz]
#pragma unroll
    for (int fp = 0; fp < 2; ++fp) {
      if (fp) __syncthreads();
      if (wf == fp) {
#pragma unroll
        for (int u = 0; u < 4; ++u) {
          const int nloc = u * 16 + fq * 4;                // 0..63 within half
          const int nng = f0 + fp * 64 + nloc;
          const fx4 bb = *(const fx4*)&bias[nng];
#pragma unroll
          for (int v = 0; v < 4; ++v) {
            const int token = wt * 64 + v * 16 + fr;
            const int s = (t0b + token) & (Sq - 1);
            const fx4 pe = *(const fx4*)&pos[(size_t)s * Em + nng];
            const fx4 a = acc[u][v];
#pragma unroll
            for (int i = 0; i < 4; ++i) {
              const int row = nloc + i;
              SM[row * 264 + (token ^ ((row & 12) << 2))] = f2bf(a[i] + bb[i] + pe[i]);
            }
          }
        }
      }
      __syncthreads();
      const int s0 = t0b & (Sq - 1);
#pragma unroll
      for (int it = 0; it < 4; ++it) {
        const int flat = it * 512 + t;
        const int row = flat >> 5, ch = flat & 31;
        bfx8 val = *(const bfx8*)&SM[row * 264 + ((ch * 8) ^ ((row & 12) << 2))];
        const int nng = f0 + fp * 64 + row;
        const int h = nng >> 6, d = nng & 63;
        *(bfx8*)&dst[(((size_t)b * Hn + h) * Dh + d) * Sq + s0 + ch * 8] = val;
      }
    }
  }
}

// ---------------- gemm_out: 64x128 tile, 512 blocks (R14, unchanged) ----------------
__global__ __launch_bounds__(256, 4) void gemm_out_bf16(
    const short* __restrict__ wv, const short* __restrict__ Wob,
    const float* __restrict__ bo, float* __restrict__ out)
{
  __shared__ short As[128 * 64];   // 16KB
  __shared__ short Bs[64 * 64];    // 8KB

  const int m0 = blockIdx.x * 64;
  const int n0 = blockIdx.y * 128;
  const int t = threadIdx.x, lane = t & 63, wave = t >> 6;
  const int wr = wave >> 1, wc = wave & 1;
  const int fr = lane & 15, fq = lane >> 4;

  const int trow = t >> 3;
  const int scol = ((t & 7) ^ (trow & 7)) * 8;
  const short* gW = Wob + (size_t)(n0 + trow) * Em + scol;
  const short* gX = wv + (size_t)(m0 + trow) * Em + scol;
  const int lofs = wave * 512;

  const int sw0 = ((fq ^ (fr & 7)) * 8);
  const int sw1 = (((4 + fq) ^ (fr & 7)) * 8);

  fx4 acc[4][2] = {};

  for (int k0 = 0; k0 < Em; k0 += 64) {
#pragma unroll
    for (int g = 0; g < 4; ++g)
      gld16(gW + (size_t)(32 * g) * Em + k0, As + g * 2048 + lofs);
#pragma unroll
    for (int g = 0; g < 2; ++g)
      gld16(gX + (size_t)(32 * g) * Em + k0, Bs + g * 2048 + lofs);
    __syncthreads();

#pragma unroll
    for (int ks = 0; ks < 2; ++ks) {
      const int sw = ks ? sw1 : sw0;
      bfx8 af[4], bf[2];
#pragma unroll
      for (int u = 0; u < 4; ++u)
        af[u] = *(const bfx8*)&As[(wr * 64 + u * 16 + fr) * 64 + sw];
#pragma unroll
      for (int v = 0; v < 2; ++v)
        bf[v] = *(const bfx8*)&Bs[(wc * 32 + v * 16 + fr) * 64 + sw];
#pragma unroll
      for (int u = 0; u < 4; ++u)
#pragma unroll
        for (int v = 0; v < 2; ++v)
          acc[u][v] = __builtin_amdgcn_mfma_f32_16x16x32_bf16(af[u], bf[v], acc[u][v], 0, 0, 0);
    }
    __syncthreads();
  }

#pragma unroll
  for (int u = 0; u < 4; ++u) {
    const int nn = n0 + wr * 64 + u * 16 + fq * 4;
    const fx4 bb = *(const fx4*)&bo[nn];
#pragma unroll
    for (int v = 0; v < 2; ++v) {
      const int m = m0 + wc * 32 + v * 16 + fr;
      fx4 val = acc[u][v];
      val[0] += bb[0]; val[1] += bb[1]; val[2] += bb[2]; val[3] += bb[3];
      *(fx4*)&out[(size_t)m * Em + nn] = val;
    }
  }
}

// ---------------- Attention (R12, unchanged) ----------------
constexpr int KVB = 64, LDK = 72;

__global__ __launch_bounds__(512) void attn_kernel(
    const short* __restrict__ qb, const short* __restrict__ kb,
    const short* __restrict__ vb, short* __restrict__ wv)
{
  __shared__ short Ks[KVB * LDK];
  __shared__ short Vt[Dh * LDK];
  __shared__ short Ps[8][16 * LDK];

  const int bh = blockIdx.x;
  const int qt = blockIdx.y;
  const int t = threadIdx.x, lane = t & 63, wave = t >> 6;
  const int fr = lane & 15, fq = lane >> 4;

  const size_t base = (size_t)bh * Sq * Dh;
  const int q0 = qt * 128 + wave * 16;

  bfx8 qf[2];
  {
    const short* qp = qb + base + (size_t)(q0 + fr) * Dh;
    qf[0] = *(const bfx8*)(qp + fq * 8);
    qf[1] = *(const bfx8*)(qp + 32 + fq * 8);
  }

  const int kr = t >> 3, kc = (t & 7) * 8;
  const short* kbp = kb + base + (size_t)kr * Dh + kc;
  const short* vbp = vb + base + (size_t)kr * Sq + kc;

  {
    bfx8 k0 = *(const bfx8*)kbp;
    bfx8 v0 = *(const bfx8*)vbp;
    *(bfx8*)&Ks[kr * LDK + kc] = k0;
    *(bfx8*)&Vt[kr * LDK + kc] = v0;
  }
  __syncthreads();

  float mrow[4] = { -1e30f, -1e30f, -1e30f, -1e30f };
  float lrow[4] = { 0.f, 0.f, 0.f, 0.f };
  fx4 oacc[4] = {};

  for (int kv0 = 0; kv0 < Sq; kv0 += KVB) {
    const bool more = (kv0 + KVB) < Sq;
    bfx8 nk0, nv0;
    if (more) {
      nk0 = *(const bfx8*)(kbp + (size_t)(kv0 + KVB) * Dh);
      nv0 = *(const bfx8*)(vbp + kv0 + KVB);
    }

    fx4 sa[4] = {};
    __builtin_amdgcn_s_setprio(1);
#pragma unroll
    for (int nf = 0; nf < 4; ++nf) {
#pragma unroll
      for (int ks = 0; ks < 2; ++ks) {
        bfx8 kf = *(const bfx8*)&Ks[(nf * 16 + fr) * LDK + ks * 32 + fq * 8];
        sa[nf] = __builtin_amdgcn_mfma_f32_16x16x32_bf16(qf[ks], kf, sa[nf], 0, 0, 0);
      }
    }
    __builtin_amdgcn_s_setprio(0);

#pragma unroll
    for (int i = 0; i < 4; ++i) {
      float mx = fmaxf(fmaxf(sa[0][i], sa[1][i]), fmaxf(sa[2][i], sa[3][i]));
      mx = fmaxf(mx, __shfl_xor(mx, 1));
      mx = fmaxf(mx, __shfl_xor(mx, 2));
      mx = fmaxf(mx, __shfl_xor(mx, 4));
      mx = fmaxf(mx, __shfl_xor(mx, 8));
      mx *= 0.125f;
      if (mx > mrow[i] + 8.f) {
        const float alpha = __expf(mrow[i] - mx);
        mrow[i] = mx;
        lrow[i] *= alpha;
#pragma unroll
        for (int df = 0; df < 4; ++df) oacc[df][i] *= alpha;
      }
      float rs = 0.f;
#pragma unroll
      for (int nf = 0; nf < 4; ++nf) {
        const float p = __expf(sa[nf][i] * 0.125f - mrow[i]);
        rs += p;
        Ps[wave][(fq * 4 + i) * LDK + nf * 16 + fr] = f2bf(p);
      }
      rs += __shfl_xor(rs, 1);
      rs += __shfl_xor(rs, 2);
      rs += __shfl_xor(rs, 4);
      rs += __shfl_xor(rs, 8);
      lrow[i] += rs;
    }

    bfx8 pf[2];
    pf[0] = *(const bfx8*)&Ps[wave][fr * LDK + fq * 8];
    pf[1] = *(const bfx8*)&Ps[wave][fr * LDK + 32 + fq * 8];
    __builtin_amdgcn_s_setprio(1);
#pragma unroll
    for (int df = 0; df < 4; ++df) {
#pragma unroll
      for (int ks = 0; ks < 2; ++ks) {
        bfx8 vf = *(const bfx8*)&Vt[(df * 16 + fr) * LDK + ks * 32 + fq * 8];
        oacc[df] = __builtin_amdgcn_mfma_f32_16x16x32_bf16(pf[ks], vf, oacc[df], 0, 0, 0);
      }
    }
    __builtin_amdgcn_s_setprio(0);
    __syncthreads();

    if (more) {
      *(bfx8*)&Ks[kr * LDK + kc] = nk0;
      *(bfx8*)&Vt[kr * LDK + kc] = nv0;
      __syncthreads();
    }
  }

  const int b = bh >> 4, h = bh & 15;
#pragma unroll
  for (int df = 0; df < 4; ++df) {
    const int d = df * 16 + fr;
#pragma unroll
    for (int i = 0; i < 4; ++i) {
      const int qrow = q0 + fq * 4 + i;
      const float o = oacc[df][i] / lrow[i];
      wv[((size_t)b * Sq + qrow) * Em + h * Dh + d] = f2bf(o);
    }
  }
}

extern "C" void kernel_launch(void* const* d_in, const int* in_sizes, int n_in,
                              void* d_out, int out_size, void* d_ws, size_t ws_size,
                              hipStream_t stream) {
  (void)in_sizes; (void)n_in; (void)out_size; (void)ws_size;
  const float* query = (const float*)d_in[0];
  const float* key   = (const float*)d_in[1];
  const float* value = (const float*)d_in[2];
  const float* Wq = (const float*)d_in[3];
  const float* bq = (const float*)d_in[4];
  const float* Wk = (const float*)d_in[5];
  const float* bk = (const float*)d_in[6];
  const float* Wv = (const float*)d_in[7];
  const float* bv = (const float*)d_in[8];
  const float* Wo = (const float*)d_in[9];
  const float* bo = (const float*)d_in[10];
  const float* pos = (const float*)d_in[11];

  short* qx = (short*)d_ws;
  short* kx = qx + NE;
  short* vx = kx + NE;
  short* Wqb = vx + NE;
  short* Wkb = Wqb + WE;
  short* Wvb = Wkb + WE;
  short* Wob = Wvb + WE;
  short* qb = Wob + WE;
  short* wv = qx;                 // alias: qx dead after gemm_qkv
  short* kb = (short*)d_out;      // d_out scratch, overwritten by gemm_out
  short* vb = kb + NE;            // [B,H,Dh,S]

  convert_kernel<<<dim3(8192), 256, 0, stream>>>(
      query, key, value, Wq, Wk, Wv, Wo, qx, kx, vx, Wqb, Wkb, Wvb, Wob);
  gemm_qkv_bf16<<<dim3(Mrows / 256, Em / 128, 3), 512, 0, stream>>>(
      qx, kx, vx, Wqb, Wkb, Wvb, bq, bk, bv, pos, qb, kb, vb);
  attn_kernel<<<dim3(Bz * Hn, Sq / 128), 512, 0, stream>>>(qb, kb, vb, wv);
  gemm_out_bf16<<<dim3(Mrows / 64, Em / 128), 256, 0, stream>>>(
      wv, Wob, bo, (float*)d_out);
}